// Round 1
// baseline (644.960 us; speedup 1.0000x reference)
//
#include <hip/hip_runtime.h>
#include <cstdint>
#include <cstddef>

#define N_TOK 8192
#define DIM   1024
#define NEXP  8
#define HID   2816
#define CAP   1280   // int(1.25 * 8192 / 8)

typedef __bf16 bf16x8 __attribute__((ext_vector_type(8)));
typedef float  floatx4 __attribute__((ext_vector_type(4)));

__device__ __forceinline__ unsigned short f2bf(float f) {
  return __builtin_bit_cast(unsigned short, (__bf16)f);
}
__device__ __forceinline__ float bf2f(unsigned short u) {
  return (float)__builtin_bit_cast(__bf16, u);
}

// async global->LDS, 16B per lane. LDS dest must be wave-uniform base + lane*16.
__device__ __forceinline__ void async16(void* lds, const void* g) {
  __builtin_amdgcn_global_load_lds(
      (const __attribute__((address_space(1))) void*)g,
      (__attribute__((address_space(3))) void*)lds, 16, 0, 0);
}

// ---------------------------------------------------------------------------
// Routing: FCFS position of each token in its expert queue. One block, 256 thr,
// 32 tokens/thread, per-thread histogram + per-expert serial scan (E=8 small).
// idx_stride handles a possible int64 index buffer (low word at even index).
// ---------------------------------------------------------------------------
__global__ void route_kernel(const int* __restrict__ idx, int idx_stride,
                             int* __restrict__ slot,
                             int* __restrict__ slot_token,
                             int* __restrict__ counts) {
  __shared__ int hist[256][NEXP];
  const int t = threadIdx.x;
  int loc[NEXP];
#pragma unroll
  for (int e = 0; e < NEXP; e++) loc[e] = 0;
  const int base = t * 32;
  for (int i = 0; i < 32; i++) {
    int e = idx[(base + i) * idx_stride];
    loc[e]++;
  }
#pragma unroll
  for (int e = 0; e < NEXP; e++) hist[t][e] = loc[e];
  __syncthreads();
  if (t < NEXP) {
    int run = 0;
    for (int i = 0; i < 256; i++) { int v = hist[i][t]; hist[i][t] = run; run += v; }
    counts[t] = run < CAP ? run : CAP;
  }
  __syncthreads();
  int b2[NEXP];
#pragma unroll
  for (int e = 0; e < NEXP; e++) b2[e] = hist[t][e];
  for (int i = 0; i < 32; i++) {
    const int n = base + i;
    const int e = idx[n * idx_stride];
    const int p = b2[e]++;
    if (p < CAP) {
      const int s = e * CAP + p;
      slot[n] = s;
      slot_token[s] = n;
    } else {
      slot[n] = -1;  // dropped -> passthrough
    }
  }
}

// ---------------------------------------------------------------------------
// Dispatch: kept tokens -> bf16 xe[slot]; dropped tokens -> y = x (fp32).
// One block per token, 256 thr * float4 = 1024 elems.
// ---------------------------------------------------------------------------
__global__ void dispatch_kernel(const float* __restrict__ x,
                                const int* __restrict__ slot,
                                unsigned short* __restrict__ xe,
                                float* __restrict__ y) {
  const int n = blockIdx.x;
  const int t = threadIdx.x;
  const int s = slot[n];
  const float4 v = ((const float4*)(x + (size_t)n * DIM))[t];
  if (s >= 0) {
    ushort4 b;
    b.x = f2bf(v.x); b.y = f2bf(v.y); b.z = f2bf(v.z); b.w = f2bf(v.w);
    ((ushort4*)(xe + (size_t)s * DIM))[t] = b;
  } else {
    ((float4*)(y + (size_t)n * DIM))[t] = v;
  }
}

// ---------------------------------------------------------------------------
// Transpose + fp32->bf16 convert: in [E][R][C] fp32 -> out [E][C][R] bf16.
// Block (32,8), 32x32 tiles via LDS (+1 pad).
// ---------------------------------------------------------------------------
__global__ void transpose_cvt(const float* __restrict__ in,
                              unsigned short* __restrict__ out,
                              const int R, const int C) {
  __shared__ float tile[32][33];
  const int e = blockIdx.z;
  const float* ib = in + (size_t)e * R * C;
  unsigned short* ob = out + (size_t)e * R * C;
  const int tx = threadIdx.x, ty = threadIdx.y;
  const int c0 = blockIdx.x * 32, r0 = blockIdx.y * 32;
#pragma unroll
  for (int i = 0; i < 4; i++)
    tile[ty + i * 8][tx] = ib[(size_t)(r0 + ty + i * 8) * C + c0 + tx];
  __syncthreads();
#pragma unroll
  for (int i = 0; i < 4; i++)
    ob[(size_t)(c0 + ty + i * 8) * R + r0 + tx] = f2bf(tile[tx][ty + i * 8]);
}

// ---------------------------------------------------------------------------
// Grouped GEMM, m97 structure: 128x128 tile, BK=32, 4 waves (2x2), each wave
// 4x4 of 16x16x32 bf16 MFMA. A [E][M][K] bf16 K-major, Bt [E][N][K] bf16
// K-major. Per-expert M trimmed to counts[e] (garbage rows beyond count are
// computed but never gathered).
// EPI 0: write gate acc as bf16 -> obuf (hbuf)
// EPI 1: read g from obuf, act = silu(g)*u, write bf16 in-place -> obuf
// EPI 2: y[slot_token[row]] = acc * score   (row < counts[e] only)
// ---------------------------------------------------------------------------
template <int EPI>
__global__ __launch_bounds__(256)
void moe_gemm(const unsigned short* __restrict__ A,
              const unsigned short* __restrict__ Bt,
              const int* __restrict__ counts,
              const int K, const int N,
              const size_t a_es, const size_t b_es,
              unsigned short* __restrict__ obuf,
              const int* __restrict__ slot_token,
              const float* __restrict__ scores,
              float* __restrict__ y) {
  const int e = blockIdx.z;
  const int cnt = counts[e];
  const int m0 = blockIdx.y * 128;
  if (m0 >= cnt) return;                 // block-uniform: safe vs barriers
  const int n0 = blockIdx.x * 128;

  __shared__ char smem[16384];           // A tile 8KB + B tile 8KB

  const int t = threadIdx.x;
  const int lane = t & 63;
  const int w = t >> 6;
  const int wr = w >> 1;                 // wave row (0..1), 64 rows each
  const int wc = w & 1;                  // wave col (0..1), 64 cols each

  // staging: thread t -> LDS chunk t*16 (row t/4, 16B chunk t%4) and +4096.
  const unsigned short* aP  = A + e * a_es + (size_t)(m0 + (t >> 2)) * K + (t & 3) * 8;
  const unsigned short* bP  = Bt + e * b_es + (size_t)(n0 + (t >> 2)) * K + (t & 3) * 8;
  const unsigned short* aP1 = aP + (size_t)64 * K;
  const unsigned short* bP1 = bP + (size_t)64 * K;
  char* lA0 = smem + t * 16;
  char* lA1 = smem + 4096 + t * 16;
  char* lB0 = smem + 8192 + t * 16;
  char* lB1 = smem + 12288 + t * 16;

  floatx4 acc[4][4] = {};

  const int mrow = wr * 64 + (lane & 15);    // A frag: m = lane&15 (+16*mi)
  const int ncol = wc * 64 + (lane & 15);    // B frag: n = lane&15 (+16*ni)
  const int kq = (lane >> 4) * 16;           // k-quad byte offset within 64B row

  for (int kk = 0; kk < K; kk += 32) {
    async16(lA0, aP); async16(lA1, aP1);
    async16(lB0, bP); async16(lB1, bP1);
    aP += 32; aP1 += 32; bP += 32; bP1 += 32;
    __syncthreads();                         // compiler drains vmcnt here
    bf16x8 af[4], bfr[4];
#pragma unroll
    for (int i = 0; i < 4; i++)
      af[i] = *(const bf16x8*)(smem + (mrow + i * 16) * 64 + kq);
#pragma unroll
    for (int i = 0; i < 4; i++)
      bfr[i] = *(const bf16x8*)(smem + 8192 + (ncol + i * 16) * 64 + kq);
#pragma unroll
    for (int mi = 0; mi < 4; mi++)
#pragma unroll
      for (int ni = 0; ni < 4; ni++)
        acc[mi][ni] = __builtin_amdgcn_mfma_f32_16x16x32_bf16(
            af[mi], bfr[ni], acc[mi][ni], 0, 0, 0);
    __syncthreads();
  }

  // C/D layout (verified m89/m91): col = lane&15, row = (lane>>4)*4 + reg
  const int quad = lane >> 4;
  const int cl = lane & 15;

  if (EPI == 0) {
    unsigned short* ob = obuf + (size_t)e * CAP * N;
#pragma unroll
    for (int mi = 0; mi < 4; mi++)
#pragma unroll
      for (int r = 0; r < 4; r++) {
        const int row = m0 + wr * 64 + mi * 16 + quad * 4 + r;
        const size_t rb = (size_t)row * N;
#pragma unroll
        for (int ni = 0; ni < 4; ni++) {
          const int col = n0 + wc * 64 + ni * 16 + cl;
          ob[rb + col] = f2bf(acc[mi][ni][r]);
        }
      }
  } else if (EPI == 1) {
    unsigned short* ob = obuf + (size_t)e * CAP * N;
#pragma unroll
    for (int mi = 0; mi < 4; mi++)
#pragma unroll
      for (int r = 0; r < 4; r++) {
        const int row = m0 + wr * 64 + mi * 16 + quad * 4 + r;
        const size_t rb = (size_t)row * N;
#pragma unroll
        for (int ni = 0; ni < 4; ni++) {
          const int col = n0 + wc * 64 + ni * 16 + cl;
          const float g = bf2f(ob[rb + col]);
          const float u = acc[mi][ni][r];
          const float act = g / (1.0f + __expf(-g)) * u;  // silu(g)*u
          ob[rb + col] = f2bf(act);
        }
      }
  } else {
#pragma unroll
    for (int mi = 0; mi < 4; mi++)
#pragma unroll
      for (int r = 0; r < 4; r++) {
        const int row = m0 + wr * 64 + mi * 16 + quad * 4 + r;
        if (row < cnt) {                       // guard: only real tokens
          const int tok = slot_token[e * CAP + row];
          const float s = scores[tok];
          float* yr = y + (size_t)tok * DIM;
#pragma unroll
          for (int ni = 0; ni < 4; ni++) {
            const int col = n0 + wc * 64 + ni * 16 + cl;
            yr[col] = acc[mi][ni][r] * s;
          }
        }
      }
  }
}

extern "C" void kernel_launch(void* const* d_in, const int* in_sizes, int n_in,
                              void* d_out, int out_size, void* d_ws, size_t ws_size,
                              hipStream_t stream) {
  const float* x      = (const float*)d_in[0];
  const int*   idx    = (const int*)d_in[1];
  const float* scores = (const float*)d_in[2];
  const float* Wg     = (const float*)d_in[3];
  const float* Wu     = (const float*)d_in[4];
  const float* Wd     = (const float*)d_in[5];
  float* y = (float*)d_out;

  // defensive: if the int64 index array is exposed as 2*N int32 words,
  // read the low word of each pair (little-endian).
  const int idx_stride = (in_sizes[1] == 2 * N_TOK) ? 2 : 1;

  // workspace bump allocator (~221 MB total)
  char* ws = (char*)d_ws;
  size_t off = 0;
  auto alloc = [&](size_t b) -> char* {
    char* p = ws + off;
    off += (b + 255) & ~(size_t)255;
    return p;
  };
  int* counts            = (int*)alloc(NEXP * 4);
  int* slot              = (int*)alloc((size_t)N_TOK * 4);
  int* slot_token        = (int*)alloc((size_t)NEXP * CAP * 4);
  unsigned short* xe     = (unsigned short*)alloc((size_t)NEXP * CAP * DIM * 2);
  unsigned short* hbuf   = (unsigned short*)alloc((size_t)NEXP * CAP * HID * 2);
  unsigned short* wg_t   = (unsigned short*)alloc((size_t)NEXP * DIM * HID * 2);
  unsigned short* wu_t   = (unsigned short*)alloc((size_t)NEXP * DIM * HID * 2);
  unsigned short* wd_t   = (unsigned short*)alloc((size_t)NEXP * DIM * HID * 2);
  (void)ws_size; (void)n_in; (void)out_size;

  route_kernel<<<1, 256, 0, stream>>>(idx, idx_stride, slot, slot_token, counts);
  dispatch_kernel<<<N_TOK, 256, 0, stream>>>(x, slot, xe, y);

  dim3 tb(32, 8);
  // Wg,Wu: [d][h] -> [h][d] bf16 ;  Wd: [h][d] -> [d][h] bf16
  transpose_cvt<<<dim3(HID / 32, DIM / 32, NEXP), tb, 0, stream>>>(Wg, wg_t, DIM, HID);
  transpose_cvt<<<dim3(HID / 32, DIM / 32, NEXP), tb, 0, stream>>>(Wu, wu_t, DIM, HID);
  transpose_cvt<<<dim3(DIM / 32, HID / 32, NEXP), tb, 0, stream>>>(Wd, wd_t, HID, DIM);

  // gate: hbuf = xe @ Wg
  moe_gemm<0><<<dim3(HID / 128, CAP / 128, NEXP), 256, 0, stream>>>(
      xe, wg_t, counts, DIM, HID, (size_t)CAP * DIM, (size_t)DIM * HID,
      hbuf, nullptr, nullptr, nullptr);
  // up + fused silu: hbuf = silu(hbuf) * (xe @ Wu)
  moe_gemm<1><<<dim3(HID / 128, CAP / 128, NEXP), 256, 0, stream>>>(
      xe, wu_t, counts, DIM, HID, (size_t)CAP * DIM, (size_t)DIM * HID,
      hbuf, nullptr, nullptr, nullptr);
  // down + fused gather/scale: y[tok] = (hbuf @ Wd) * score
  moe_gemm<2><<<dim3(DIM / 128, CAP / 128, NEXP), 256, 0, stream>>>(
      hbuf, wd_t, counts, HID, DIM, (size_t)CAP * HID, (size_t)HID * DIM,
      nullptr, slot_token, scores, y);
}

// Round 2
// 560.928 us; speedup vs baseline: 1.1498x; 1.1498x over previous
//
#include <hip/hip_runtime.h>
#include <cstdint>
#include <cstddef>

#define N_TOK 8192
#define DIM   1024
#define NEXP  8
#define HID   2816
#define CAP   1280   // int(1.25 * 8192 / 8)

typedef __bf16 bf16x8 __attribute__((ext_vector_type(8)));
typedef float  floatx4 __attribute__((ext_vector_type(4)));
typedef unsigned short u16x8 __attribute__((ext_vector_type(8)));

__device__ __forceinline__ unsigned short f2bf(float f) {
  return __builtin_bit_cast(unsigned short, (__bf16)f);
}

// async global->LDS, 16B per lane. LDS dest must be wave-uniform base + lane*16.
__device__ __forceinline__ void async16(void* lds, const void* g) {
  __builtin_amdgcn_global_load_lds(
      (const __attribute__((address_space(1))) void*)g,
      (__attribute__((address_space(3))) void*)lds, 16, 0, 0);
}

// ---------------------------------------------------------------------------
// Routing: FCFS position of each token in its expert queue. One block, 256 thr.
// ---------------------------------------------------------------------------
__global__ void route_kernel(const int* __restrict__ idx, int idx_stride,
                             int* __restrict__ slot,
                             int* __restrict__ slot_token,
                             int* __restrict__ counts) {
  __shared__ int hist[256][NEXP];
  const int t = threadIdx.x;
  int loc[NEXP];
#pragma unroll
  for (int e = 0; e < NEXP; e++) loc[e] = 0;
  const int base = t * 32;
  for (int i = 0; i < 32; i++) {
    int e = idx[(base + i) * idx_stride];
    loc[e]++;
  }
#pragma unroll
  for (int e = 0; e < NEXP; e++) hist[t][e] = loc[e];
  __syncthreads();
  if (t < NEXP) {
    int run = 0;
    for (int i = 0; i < 256; i++) { int v = hist[i][t]; hist[i][t] = run; run += v; }
    counts[t] = run < CAP ? run : CAP;
  }
  __syncthreads();
  int b2[NEXP];
#pragma unroll
  for (int e = 0; e < NEXP; e++) b2[e] = hist[t][e];
  for (int i = 0; i < 32; i++) {
    const int n = base + i;
    const int e = idx[n * idx_stride];
    const int p = b2[e]++;
    if (p < CAP) {
      const int s = e * CAP + p;
      slot[n] = s;
      slot_token[s] = n;
    } else {
      slot[n] = -1;  // dropped -> passthrough
    }
  }
}

// ---------------------------------------------------------------------------
// Dispatch: kept tokens -> bf16 xe[slot]; dropped tokens -> y = x (fp32).
// ---------------------------------------------------------------------------
__global__ void dispatch_kernel(const float* __restrict__ x,
                                const int* __restrict__ slot,
                                unsigned short* __restrict__ xe,
                                float* __restrict__ y) {
  const int n = blockIdx.x;
  const int t = threadIdx.x;
  const int s = slot[n];
  const float4 v = ((const float4*)(x + (size_t)n * DIM))[t];
  if (s >= 0) {
    ushort4 b;
    b.x = f2bf(v.x); b.y = f2bf(v.y); b.z = f2bf(v.z); b.w = f2bf(v.w);
    ((ushort4*)(xe + (size_t)s * DIM))[t] = b;
  } else {
    ((float4*)(y + (size_t)n * DIM))[t] = v;
  }
}

// ---------------------------------------------------------------------------
// Transpose + fp32->bf16: in [E][R][C] fp32 -> out [E][C][R] bf16.
// 64x64 tiles, 256 thr. float4 coalesced loads; ushort8 (16B) coalesced stores.
// LDS padded [64][65]: all phases <=2-way bank aliasing (free on gfx950).
// ---------------------------------------------------------------------------
__global__ __launch_bounds__(256)
void transpose_cvt(const float* __restrict__ in,
                   unsigned short* __restrict__ out,
                   const int R, const int C) {
  __shared__ float tile[64][65];
  const int e = blockIdx.z;
  const float* ib = in + (size_t)e * R * C;
  unsigned short* ob = out + (size_t)e * R * C;
  const int t = threadIdx.x;
  const int c0 = blockIdx.x * 64, r0 = blockIdx.y * 64;
  const int lr = t >> 4;          // 0..15
  const int lc = (t & 15) * 4;    // 0..60
#pragma unroll
  for (int i = 0; i < 4; i++) {
    const float4 v = *(const float4*)(ib + (size_t)(r0 + lr + i * 16) * C + c0 + lc);
    tile[lr + i * 16][lc + 0] = v.x;
    tile[lr + i * 16][lc + 1] = v.y;
    tile[lr + i * 16][lc + 2] = v.z;
    tile[lr + i * 16][lc + 3] = v.w;
  }
  __syncthreads();
  const int oc = t >> 2;          // out row (original col) 0..63
  const int sub = t & 3;
#pragma unroll
  for (int half = 0; half < 2; half++) {
    const int rch = sub + half * 4;  // chunk of 8 original rows
    u16x8 o;
#pragma unroll
    for (int j = 0; j < 8; j++) o[j] = f2bf(tile[rch * 8 + j][oc]);
    *(u16x8*)(ob + (size_t)(c0 + oc) * R + r0 + rch * 8) = o;
  }
}

// ---------------------------------------------------------------------------
// Fused gate+up grouped GEMM. Tile 128M x 64N (x2 weight matrices), BK=32.
// A [E][CAP][d] bf16 K-major; Bg/Bu [E][h][d] bf16 K-major (pre-transposed).
// 4 waves: wr = M-half (64 rows), wc = N-half (32 cols). Per wave 4x2 acc per
// matrix. Epilogue: hact = silu(g)*u -> bf16 [E][CAP][h].
// 1-D grid, XCD-aware decode: all 10 m-blocks of one (n,e) group on one XCD.
// LDS chunk XOR-swizzle: LDS(r,c) = global(r, c ^ ((r>>1)&3)) -> 2-way banks.
// ---------------------------------------------------------------------------
__global__ __launch_bounds__(256)
void gateup_gemm(const unsigned short* __restrict__ A,
                 const unsigned short* __restrict__ Bg,
                 const unsigned short* __restrict__ Bu,
                 const int* __restrict__ counts,
                 unsigned short* __restrict__ hact) {
  // decode: G = 8 XCD * 44 colgroups * 10 mblocks
  const int bid = blockIdx.x;
  const int xcd = bid & 7;
  const int slot = bid >> 3;       // 0..439
  const int m = slot % 10;
  const int cgl = slot / 10;       // 0..43
  const int cg = xcd + 8 * cgl;    // 0..351
  const int n = cg % 44;
  const int e = cg / 44;

  const int cnt = counts[e];
  const int m0 = m * 128;
  if (m0 >= cnt) return;
  const int n0 = n * 64;

  __shared__ char smem[16384];  // A 8K | Bg 4K | Bu 4K

  const int t = threadIdx.x;
  const int lane = t & 63;
  const int w = t >> 6;
  const int wr = w >> 1;
  const int wc = w & 1;

  // staging with chunk swizzle (same swizzle for r and r+64 since s=(r>>1)&3)
  const int sr = t >> 2;                       // staging row
  const int sc = (t & 3) ^ ((sr >> 1) & 3);    // swizzled source chunk
  const unsigned short* aP  = A  + (size_t)e * CAP * DIM + (size_t)(m0 + sr) * DIM + sc * 8;
  const unsigned short* aP1 = aP + (size_t)64 * DIM;
  const unsigned short* bgP = Bg + (size_t)e * HID * DIM + (size_t)(n0 + sr) * DIM + sc * 8;
  const unsigned short* buP = Bu + (size_t)e * HID * DIM + (size_t)(n0 + sr) * DIM + sc * 8;
  char* lA0 = smem + t * 16;
  char* lA1 = smem + 4096 + t * 16;
  char* lBg = smem + 8192 + t * 16;       // only sr<64 matters; all 256 thr map 1:1
  char* lBu = smem + 12288 + t * 16;

  floatx4 accg[4][2] = {};
  floatx4 accu[4][2] = {};

  const int mrow = wr * 64 + (lane & 15);
  const int ncol = wc * 32 + (lane & 15);
  const int q = lane >> 4;
  const int kqA = ((q ^ ((mrow >> 1) & 3)) * 16);  // lane-constant across mi
  const int kqB = ((q ^ ((ncol >> 1) & 3)) * 16);

  for (int kk = 0; kk < DIM; kk += 32) {
    async16(lA0, aP); async16(lA1, aP1);
    async16(lBg, bgP); async16(lBu, buP);
    aP += 32; aP1 += 32; bgP += 32; buP += 32;
    __syncthreads();
    bf16x8 af[4], gf[2], uf[2];
#pragma unroll
    for (int i = 0; i < 4; i++)
      af[i] = *(const bf16x8*)(smem + (mrow + i * 16) * 64 + kqA);
#pragma unroll
    for (int i = 0; i < 2; i++) {
      gf[i] = *(const bf16x8*)(smem + 8192 + (ncol + i * 16) * 64 + kqB);
      uf[i] = *(const bf16x8*)(smem + 12288 + (ncol + i * 16) * 64 + kqB);
    }
#pragma unroll
    for (int mi = 0; mi < 4; mi++)
#pragma unroll
      for (int ni = 0; ni < 2; ni++) {
        accg[mi][ni] = __builtin_amdgcn_mfma_f32_16x16x32_bf16(
            af[mi], gf[ni], accg[mi][ni], 0, 0, 0);
        accu[mi][ni] = __builtin_amdgcn_mfma_f32_16x16x32_bf16(
            af[mi], uf[ni], accu[mi][ni], 0, 0, 0);
      }
    __syncthreads();
  }

  // C/D layout: col = lane&15, row = (lane>>4)*4 + reg
  const int quad = lane >> 4;
  const int cl = lane & 15;
  unsigned short* ob = hact + (size_t)e * CAP * HID;
#pragma unroll
  for (int mi = 0; mi < 4; mi++)
#pragma unroll
    for (int r = 0; r < 4; r++) {
      const int row = m0 + wr * 64 + mi * 16 + quad * 4 + r;
      const size_t rb = (size_t)row * HID;
#pragma unroll
      for (int ni = 0; ni < 2; ni++) {
        const int col = n0 + wc * 32 + ni * 16 + cl;
        const float g = accg[mi][ni][r];
        const float u = accu[mi][ni][r];
        ob[rb + col] = f2bf(g / (1.0f + __expf(-g)) * u);
      }
    }
}

// ---------------------------------------------------------------------------
// Down GEMM + fused gather/scale. Tile 128x128, BK=32. A = hact [E][CAP][h],
// Bt = Wd^T [E][d][h]. Epilogue: y[slot_token[row]] = acc*score (row<cnt).
// Same XCD decode (G = 8 * 8 colgroups * 10 mblocks) and LDS swizzle.
// ---------------------------------------------------------------------------
__global__ __launch_bounds__(256)
void down_gemm(const unsigned short* __restrict__ A,
               const unsigned short* __restrict__ Bt,
               const int* __restrict__ counts,
               const int* __restrict__ slot_token,
               const float* __restrict__ scores,
               float* __restrict__ y) {
  const int bid = blockIdx.x;
  const int xcd = bid & 7;
  const int slot = bid >> 3;       // 0..79
  const int m = slot % 10;
  const int cgl = slot / 10;       // 0..7
  const int cg = xcd + 8 * cgl;    // 0..63
  const int n = cg % 8;
  const int e = cg / 8;

  const int cnt = counts[e];
  const int m0 = m * 128;
  if (m0 >= cnt) return;
  const int n0 = n * 128;

  __shared__ char smem[16384];  // A 8K | B 8K

  const int t = threadIdx.x;
  const int lane = t & 63;
  const int w = t >> 6;
  const int wr = w >> 1;
  const int wc = w & 1;

  const int sr = t >> 2;
  const int sc = (t & 3) ^ ((sr >> 1) & 3);
  const unsigned short* aP  = A + (size_t)e * CAP * HID + (size_t)(m0 + sr) * HID + sc * 8;
  const unsigned short* aP1 = aP + (size_t)64 * HID;
  const unsigned short* bP  = Bt + (size_t)e * DIM * HID + (size_t)(n0 + sr) * HID + sc * 8;
  const unsigned short* bP1 = bP + (size_t)64 * HID;
  char* lA0 = smem + t * 16;
  char* lA1 = smem + 4096 + t * 16;
  char* lB0 = smem + 8192 + t * 16;
  char* lB1 = smem + 12288 + t * 16;

  floatx4 acc[4][4] = {};

  const int mrow = wr * 64 + (lane & 15);
  const int ncol = wc * 64 + (lane & 15);
  const int q = lane >> 4;
  const int kqA = ((q ^ ((mrow >> 1) & 3)) * 16);
  const int kqB = ((q ^ ((ncol >> 1) & 3)) * 16);

  for (int kk = 0; kk < HID; kk += 32) {
    async16(lA0, aP); async16(lA1, aP1);
    async16(lB0, bP); async16(lB1, bP1);
    aP += 32; aP1 += 32; bP += 32; bP1 += 32;
    __syncthreads();
    bf16x8 af[4], bfr[4];
#pragma unroll
    for (int i = 0; i < 4; i++)
      af[i] = *(const bf16x8*)(smem + (mrow + i * 16) * 64 + kqA);
#pragma unroll
    for (int i = 0; i < 4; i++)
      bfr[i] = *(const bf16x8*)(smem + 8192 + (ncol + i * 16) * 64 + kqB);
#pragma unroll
    for (int mi = 0; mi < 4; mi++)
#pragma unroll
      for (int ni = 0; ni < 4; ni++)
        acc[mi][ni] = __builtin_amdgcn_mfma_f32_16x16x32_bf16(
            af[mi], bfr[ni], acc[mi][ni], 0, 0, 0);
    __syncthreads();
  }

  const int quad = lane >> 4;
  const int cl = lane & 15;
#pragma unroll
  for (int mi = 0; mi < 4; mi++)
#pragma unroll
    for (int r = 0; r < 4; r++) {
      const int row = m0 + wr * 64 + mi * 16 + quad * 4 + r;
      if (row < cnt) {
        const int tok = slot_token[e * CAP + row];
        const float s = scores[tok];
        float* yr = y + (size_t)tok * DIM;
#pragma unroll
        for (int ni = 0; ni < 4; ni++) {
          const int col = n0 + wc * 64 + ni * 16 + cl;
          yr[col] = acc[mi][ni][r] * s;
        }
      }
    }
}

extern "C" void kernel_launch(void* const* d_in, const int* in_sizes, int n_in,
                              void* d_out, int out_size, void* d_ws, size_t ws_size,
                              hipStream_t stream) {
  const float* x      = (const float*)d_in[0];
  const int*   idx    = (const int*)d_in[1];
  const float* scores = (const float*)d_in[2];
  const float* Wg     = (const float*)d_in[3];
  const float* Wu     = (const float*)d_in[4];
  const float* Wd     = (const float*)d_in[5];
  float* y = (float*)d_out;

  const int idx_stride = (in_sizes[1] == 2 * N_TOK) ? 2 : 1;

  char* ws = (char*)d_ws;
  size_t off = 0;
  auto alloc = [&](size_t b) -> char* {
    char* p = ws + off;
    off += (b + 255) & ~(size_t)255;
    return p;
  };
  int* counts            = (int*)alloc(NEXP * 4);
  int* slot              = (int*)alloc((size_t)N_TOK * 4);
  int* slot_token        = (int*)alloc((size_t)NEXP * CAP * 4);
  unsigned short* xe     = (unsigned short*)alloc((size_t)NEXP * CAP * DIM * 2);
  unsigned short* hact   = (unsigned short*)alloc((size_t)NEXP * CAP * HID * 2);
  unsigned short* wg_t   = (unsigned short*)alloc((size_t)NEXP * DIM * HID * 2);
  unsigned short* wu_t   = (unsigned short*)alloc((size_t)NEXP * DIM * HID * 2);
  unsigned short* wd_t   = (unsigned short*)alloc((size_t)NEXP * DIM * HID * 2);
  (void)ws_size; (void)n_in; (void)out_size;

  route_kernel<<<1, 256, 0, stream>>>(idx, idx_stride, slot, slot_token, counts);
  dispatch_kernel<<<N_TOK, 256, 0, stream>>>(x, slot, xe, y);

  // Wg,Wu: [d][h] -> [h][d] bf16 ;  Wd: [h][d] -> [d][h] bf16
  transpose_cvt<<<dim3(HID / 64, DIM / 64, NEXP), 256, 0, stream>>>(Wg, wg_t, DIM, HID);
  transpose_cvt<<<dim3(HID / 64, DIM / 64, NEXP), 256, 0, stream>>>(Wu, wu_t, DIM, HID);
  transpose_cvt<<<dim3(DIM / 64, HID / 64, NEXP), 256, 0, stream>>>(Wd, wd_t, HID, DIM);

  // fused gate+up: hact = silu(xe@Wg) * (xe@Wu)
  gateup_gemm<<<8 * 44 * 10, 256, 0, stream>>>(xe, wg_t, wu_t, counts, hact);
  // down + fused gather/scale: y[tok] = (hact @ Wd) * score
  down_gemm<<<8 * 8 * 10, 256, 0, stream>>>(hact, wd_t, counts, slot_token, scores, y);
}